// Round 1
// baseline (4860.812 us; speedup 1.0000x reference)
//
#include <hip/hip_runtime.h>
#include <hip/hip_bf16.h>
#include <math.h>

#define BB 16
#define CC 256
#define C4 64
#define HH 96
#define WW 96
#define HW 9216
#define EPSF 1e-5f

// ---------------- per-channel mean + inv_std (var uses n-1) ----------------
__global__ void channel_stats_kernel(const float* __restrict__ x,
                                     float* __restrict__ mean_out,
                                     float* __restrict__ istd_out) {
    int bc = blockIdx.x;
    const float* p = x + (size_t)bc * HW;
    float s = 0.f, ss = 0.f;
    for (int i = threadIdx.x; i < HW; i += 256) { float v = p[i]; s += v; ss += v * v; }
    __shared__ float red[256], red2[256];
    red[threadIdx.x] = s; red2[threadIdx.x] = ss;
    __syncthreads();
    for (int off = 128; off > 0; off >>= 1) {
        if (threadIdx.x < off) { red[threadIdx.x] += red[threadIdx.x + off]; red2[threadIdx.x] += red2[threadIdx.x + off]; }
        __syncthreads();
    }
    if (threadIdx.x == 0) {
        float sum = red[0], sumsq = red2[0];
        float m = sum / (float)HW;
        float var = (sumsq - sum * m) / (float)(HW - 1);
        mean_out[bc] = m;
        istd_out[bc] = rsqrtf(var + EPSF);
    }
}

// ---------------- router softmax + freq-weight softmax ----------------
__global__ void router_kernel(const float* __restrict__ pooled, const float* __restrict__ rw,
                              const float* __restrict__ rb, const float* __restrict__ fwts,
                              float* __restrict__ route, float* __restrict__ fw) {
    int t = threadIdx.x;
    if (t < BB) {
        float l0 = rb[0], l1 = rb[1];
        for (int c = 0; c < CC; ++c) {
            float p = pooled[t * CC + c];
            l0 += p * rw[c];
            l1 += p * rw[CC + c];
        }
        float m = fmaxf(l0, l1);
        float e0 = __expf(l0 - m), e1 = __expf(l1 - m);
        float inv = 1.f / (e0 + e1);
        route[t * 2 + 0] = e0 * inv;
        route[t * 2 + 1] = e1 * inv;
    }
    if (t == BB) {
        float a = fwts[0], b = fwts[1], c = fwts[2];
        float m = fmaxf(a, fmaxf(b, c));
        float e0 = __expf(a - m), e1 = __expf(b - m), e2 = __expf(c - m);
        float inv = 1.f / (e0 + e1 + e2);
        fw[0] = e0 * inv; fw[1] = e1 * inv; fw[2] = e2 * inv;
    }
}

// ---------------- 3x3 SAME conv, fp32, COPT output channels per thread ----------------
template <int CIN, int COUT, int COPT>
__global__ __launch_bounds__(256) void conv3x3_kernel(const float* __restrict__ x,
                                                      const float* __restrict__ wgt,
                                                      const float* __restrict__ bias,
                                                      float* __restrict__ y) {
    int p = blockIdx.x * 256 + threadIdx.x;
    int co0 = blockIdx.y * COPT;
    int b = blockIdx.z;
    int h = p / WW, w = p % WW;
    float acc[COPT];
#pragma unroll
    for (int j = 0; j < COPT; ++j) acc[j] = bias[co0 + j];
    const float* xb = x + (size_t)b * CIN * HW;
    for (int ci = 0; ci < CIN; ++ci) {
        const float* xc = xb + (size_t)ci * HW;
        const float* wc = wgt + ((size_t)co0 * CIN + ci) * 9;
        float xv[9];
#pragma unroll
        for (int dh = 0; dh < 3; ++dh) {
            int hh = h + dh - 1;
            bool hv = (hh >= 0) && (hh < HH);
#pragma unroll
            for (int dw = 0; dw < 3; ++dw) {
                int ww2 = w + dw - 1;
                bool v = hv && (ww2 >= 0) && (ww2 < WW);
                xv[dh * 3 + dw] = v ? xc[hh * WW + ww2] : 0.f;
            }
        }
        float wv[COPT][9];
#pragma unroll
        for (int j = 0; j < COPT; ++j)
#pragma unroll
            for (int t = 0; t < 9; ++t) wv[j][t] = wc[(size_t)j * CIN * 9 + t];
#pragma unroll
        for (int j = 0; j < COPT; ++j)
#pragma unroll
            for (int t = 0; t < 9; ++t) acc[j] += xv[t] * wv[j][t];
    }
    float* yb = y + ((size_t)b * COUT + co0) * HW + p;
#pragma unroll
    for (int j = 0; j < COPT; ++j) yb[(size_t)j * HW] = acc[j];
}

// ---------------- AFN tiny MLP: hidden = relu(s1 @ mean + b1); stats = s2 @ hidden + b2 ----------------
template <int CH, int HID>
__global__ void afn_mlp_kernel(const float* __restrict__ mean,
                               const float* __restrict__ s1w, const float* __restrict__ s1b,
                               const float* __restrict__ s2w, const float* __restrict__ s2b,
                               float* __restrict__ ag, float* __restrict__ ab) {
    int b = blockIdx.x;
    __shared__ float hbuf[HID];
    int t = threadIdx.x;
    if (t < HID) {
        float s = s1b[t];
        for (int c = 0; c < CH; ++c) s += mean[b * CH + c] * s1w[t * CH + c];
        hbuf[t] = fmaxf(s, 0.f);
    }
    __syncthreads();
    if (t < 2 * CH) {
        float s = s2b[t];
#pragma unroll
        for (int k = 0; k < HID; ++k) s += hbuf[k] * s2w[t * HID + k];
        if (t < CH) ag[b * CH + t] = s;
        else        ab[b * CH + (t - CH)] = s;
    }
}

// ---------------- AFN apply (+ optional exact GELU), in place ----------------
template <int CH, bool GELU>
__global__ void afn_apply_kernel(float* __restrict__ hbuf_g, const float* __restrict__ mean,
                                 const float* __restrict__ istd, const float* __restrict__ ag,
                                 const float* __restrict__ ab, const float* __restrict__ gamma,
                                 const float* __restrict__ beta) {
    int p = blockIdx.x * 256 + threadIdx.x;
    int c = blockIdx.y, b = blockIdx.z;
    int bc = b * CH + c;
    float scale = (1.f + ag[bc]) * gamma[c] * istd[bc];
    float shift = ab[bc] * beta[c];
    float m = mean[bc];
    float* ptr = hbuf_g + (size_t)bc * HW + p;
    float v = (*ptr - m) * scale + shift;
    if (GELU) v = 0.5f * v * (1.f + erff(v * 0.70710678118654752f));
    *ptr = v;
}

// ---------------- out = x + route0 * out1 ----------------
__global__ void combine_kernel(const float* __restrict__ x, const float* __restrict__ out1,
                               const float* __restrict__ route, float* __restrict__ out) {
    int b = blockIdx.y;
    size_t i = (size_t)b * CC * HW + (size_t)blockIdx.x * 256 + threadIdx.x;
    float r0 = route[b * 2];
    out[i] = x[i] + r0 * out1[i];
}

// ---------------- 1x1 conv x(f32,256ch) -> qkv bf16 (768ch) ----------------
template <int COPT>
__global__ __launch_bounds__(256) void qkv_kernel(const float* __restrict__ x,
                                                  const float* __restrict__ wgt,
                                                  const float* __restrict__ bias,
                                                  __hip_bfloat16* __restrict__ qkv) {
    int p = blockIdx.x * 256 + threadIdx.x;
    int co0 = blockIdx.y * COPT;
    int b = blockIdx.z;
    float acc[COPT];
#pragma unroll
    for (int j = 0; j < COPT; ++j) acc[j] = bias[co0 + j];
    const float* xb = x + (size_t)b * CC * HW + p;
    for (int ci = 0; ci < CC; ++ci) {
        float xv = xb[(size_t)ci * HW];
#pragma unroll
        for (int j = 0; j < COPT; ++j) acc[j] += xv * wgt[(size_t)(co0 + j) * CC + ci];
    }
    __hip_bfloat16* yb = qkv + ((size_t)b * 768 + co0) * HW + p;
#pragma unroll
    for (int j = 0; j < COPT; ++j) yb[(size_t)j * HW] = __float2bfloat16(acc[j]);
}

// ---------------- attention: one block per (b, n, d); S/PV over the H x W image rows ----------------
#define LP 98
__global__ __launch_bounds__(256) void attn_kernel(const __hip_bfloat16* __restrict__ qkv,
                                                   __hip_bfloat16* __restrict__ a) {
    int d = blockIdx.x;   // head-dim channel 0..31
    int n = blockIdx.y;   // head 0..7
    int b = blockIdx.z;
    __shared__ __hip_bfloat16 qs[96 * LP];   // later reused for V
    __shared__ __hip_bfloat16 ks[96 * LP];
    __shared__ __hip_bfloat16 ss[96 * LP];
    int t = threadIdx.x;
    const __hip_bfloat16* qp = qkv + ((size_t)b * 768 + n * 32 + d) * HW;
    const __hip_bfloat16* kp = qp + (size_t)256 * HW;
    const __hip_bfloat16* vp = qp + (size_t)512 * HW;
    for (int i = t; i < HW; i += 256) {
        int r = i / 96, cc = i % 96;
        qs[r * LP + cc] = qp[i];
        ks[r * LP + cc] = kp[i];
    }
    __syncthreads();
    int tx = t & 15, ty = t >> 4;
    int h0 = ty * 6, g0 = tx * 6;
    float acc[6][6];
#pragma unroll
    for (int i = 0; i < 6; ++i)
#pragma unroll
        for (int j = 0; j < 6; ++j) acc[i][j] = 0.f;
    for (int w = 0; w < 96; ++w) {
        float qv[6], kv[6];
#pragma unroll
        for (int i = 0; i < 6; ++i) qv[i] = __bfloat162float(qs[(h0 + i) * LP + w]);
#pragma unroll
        for (int j = 0; j < 6; ++j) kv[j] = __bfloat162float(ks[(g0 + j) * LP + w]);
#pragma unroll
        for (int i = 0; i < 6; ++i)
#pragma unroll
            for (int j = 0; j < 6; ++j) acc[i][j] += qv[i] * kv[j];
    }
    const float scale = 0.0625f;  // 256^-0.5
#pragma unroll
    for (int i = 0; i < 6; ++i)
#pragma unroll
        for (int j = 0; j < 6; ++j)
            ss[(h0 + i) * LP + g0 + j] = __float2bfloat16(acc[i][j] * scale);
    __syncthreads();
    if (t < 96) {
        float m = -1e30f;
        for (int g = 0; g < 96; ++g) m = fmaxf(m, __bfloat162float(ss[t * LP + g]));
        float sum = 0.f;
        float e[96];
        for (int g = 0; g < 96; ++g) { e[g] = __expf(__bfloat162float(ss[t * LP + g]) - m); sum += e[g]; }
        float inv = 1.f / sum;
        for (int g = 0; g < 96; ++g) ss[t * LP + g] = __float2bfloat16(e[g] * inv);
    }
    __syncthreads();
    for (int i = t; i < HW; i += 256) {
        int r = i / 96, cc = i % 96;
        qs[r * LP + cc] = vp[i];  // V overwrites Q
    }
    __syncthreads();
    int w0 = tx * 6;
#pragma unroll
    for (int i = 0; i < 6; ++i)
#pragma unroll
        for (int j = 0; j < 6; ++j) acc[i][j] = 0.f;
    for (int g = 0; g < 96; ++g) {
        float pv[6], vv[6];
#pragma unroll
        for (int i = 0; i < 6; ++i) pv[i] = __bfloat162float(ss[(h0 + i) * LP + g]);
#pragma unroll
        for (int j = 0; j < 6; ++j) vv[j] = __bfloat162float(qs[g * LP + w0 + j]);
#pragma unroll
        for (int i = 0; i < 6; ++i)
#pragma unroll
            for (int j = 0; j < 6; ++j) acc[i][j] += pv[i] * vv[j];
    }
    // output channel after transpose(0,2,1,3,4): c' = d*8 + n
    __hip_bfloat16* ap = a + ((size_t)b * CC + (d * 8 + n)) * HW;
#pragma unroll
    for (int i = 0; i < 6; ++i)
#pragma unroll
        for (int j = 0; j < 6; ++j)
            ap[(h0 + i) * 96 + w0 + j] = __float2bfloat16(acc[i][j]);
}

// ---------------- proj 1x1 (bf16 a -> f32), accumulate route1 * result into out ----------------
template <int COPT>
__global__ __launch_bounds__(256) void proj_acc_kernel(const __hip_bfloat16* __restrict__ a,
                                                       const float* __restrict__ wgt,
                                                       const float* __restrict__ bias,
                                                       const float* __restrict__ route,
                                                       float* __restrict__ out) {
    int p = blockIdx.x * 256 + threadIdx.x;
    int co0 = blockIdx.y * COPT;
    int b = blockIdx.z;
    float acc[COPT];
#pragma unroll
    for (int j = 0; j < COPT; ++j) acc[j] = bias[co0 + j];
    const float* dummy = nullptr; (void)dummy;
    const __hip_bfloat16* abp = a + (size_t)b * CC * HW + p;
    for (int ci = 0; ci < CC; ++ci) {
        float xv = __bfloat162float(abp[(size_t)ci * HW]);
#pragma unroll
        for (int j = 0; j < COPT; ++j) acc[j] += xv * wgt[(size_t)(co0 + j) * CC + ci];
    }
    float r1 = route[b * 2 + 1];
    float* ob = out + ((size_t)b * CC + co0) * HW + p;
#pragma unroll
    for (int j = 0; j < COPT; ++j) ob[(size_t)j * HW] += r1 * acc[j];
}

// ---------------- grouped 3x3 conv (64 groups of 4 in-ch -> 1 out-ch) + exact GELU ----------------
__global__ __launch_bounds__(256) void freqdw_kernel(const float* __restrict__ x,
                                                     const float* __restrict__ wgt,  // (64,4,3,3)
                                                     const float* __restrict__ bias, // (64)
                                                     float* __restrict__ f) {
    int p = blockIdx.x * 256 + threadIdx.x;
    int g = blockIdx.y;
    int b = blockIdx.z;
    int h = p / WW, w = p % WW;
    float acc = bias[g];
    const float* wq = wgt + g * 36;
#pragma unroll
    for (int q = 0; q < 4; ++q) {
        const float* xc = x + ((size_t)b * CC + 4 * g + q) * HW;
#pragma unroll
        for (int dh = 0; dh < 3; ++dh) {
            int hh = h + dh - 1;
            bool hv = (hh >= 0) && (hh < HH);
#pragma unroll
            for (int dw = 0; dw < 3; ++dw) {
                int ww2 = w + dw - 1;
                bool v = hv && (ww2 >= 0) && (ww2 < WW);
                float xv = v ? xc[hh * WW + ww2] : 0.f;
                acc += xv * wq[q * 9 + dh * 3 + dw];
            }
        }
    }
    acc = 0.5f * acc * (1.f + erff(acc * 0.70710678118654752f));
    f[((size_t)b * C4 + g) * HW + p] = acc;
}

// ---------------- freq pointwise 1x1 (64 -> 256), accumulate route1*fw[i]*result into out --------
template <int COPT>
__global__ __launch_bounds__(256) void freqpw_acc_kernel(const float* __restrict__ f,
                                                         const float* __restrict__ wgt,  // (256,64)
                                                         const float* __restrict__ bias, // (256)
                                                         const float* __restrict__ route,
                                                         const float* __restrict__ fw, int which,
                                                         float* __restrict__ out) {
    int p = blockIdx.x * 256 + threadIdx.x;
    int co0 = blockIdx.y * COPT;
    int b = blockIdx.z;
    float acc[COPT];
#pragma unroll
    for (int j = 0; j < COPT; ++j) acc[j] = bias[co0 + j];
    const float* fb = f + (size_t)b * C4 * HW + p;
    for (int g = 0; g < C4; ++g) {
        float xv = fb[(size_t)g * HW];
#pragma unroll
        for (int j = 0; j < COPT; ++j) acc[j] += xv * wgt[(size_t)(co0 + j) * C4 + g];
    }
    float s = route[b * 2 + 1] * fw[which];
    float* ob = out + ((size_t)b * CC + co0) * HW + p;
#pragma unroll
    for (int j = 0; j < COPT; ++j) ob[(size_t)j * HW] += s * acc[j];
}

extern "C" void kernel_launch(void* const* d_in, const int* in_sizes, int n_in,
                              void* d_out, int out_size, void* d_ws, size_t ws_size,
                              hipStream_t stream) {
    const float* x    = (const float*)d_in[0];
    const float* c1w  = (const float*)d_in[1];
    const float* c1b  = (const float*)d_in[2];
    const float* g1   = (const float*)d_in[3];
    const float* be1  = (const float*)d_in[4];
    const float* s1w1 = (const float*)d_in[5];
    const float* s1b1 = (const float*)d_in[6];
    const float* s2w1 = (const float*)d_in[7];
    const float* s2b1 = (const float*)d_in[8];
    const float* c2w  = (const float*)d_in[9];
    const float* c2b  = (const float*)d_in[10];
    const float* g2   = (const float*)d_in[11];
    const float* be2  = (const float*)d_in[12];
    const float* s1w2 = (const float*)d_in[13];
    const float* s1b2 = (const float*)d_in[14];
    const float* s2w2 = (const float*)d_in[15];
    const float* s2b2 = (const float*)d_in[16];
    const float* qkvw = (const float*)d_in[17];
    const float* qkvb = (const float*)d_in[18];
    const float* pjw  = (const float*)d_in[19];
    const float* pjb  = (const float*)d_in[20];
    const float* dww  = (const float*)d_in[21];
    const float* dwb  = (const float*)d_in[22];
    const float* pww  = (const float*)d_in[23];
    const float* pwb  = (const float*)d_in[24];
    const float* fwts = (const float*)d_in[25];
    const float* rw   = (const float*)d_in[26];
    const float* rb   = (const float*)d_in[27];
    float* out = (float*)d_out;

    char* ws = (char*)d_ws;
    // region0 [0, 226.5 MB): qkv bf16 (B,768,HW); earlier aliased as h2/out1 f32 (B,256,HW)
    __hip_bfloat16* qkv = (__hip_bfloat16*)ws;
    float* h2 = (float*)ws;
    // region1 [226.5 MB, +75.5 MB): h1 f32 (38 MB) -> a bf16 (75.5 MB) -> ftmp f32 (38 MB)
    const size_t OFF1 = 226492416ULL;
    float* h1 = (float*)(ws + OFF1);
    __hip_bfloat16* abuf = (__hip_bfloat16*)(ws + OFF1);
    float* ftmp = (float*)(ws + OFF1);
    // stats region
    const size_t OFF2 = OFF1 + 75497472ULL;  // 301,989,888
    float* stats = (float*)(ws + OFF2);
    float* pooled_x = stats;            // 4096
    float* istd_x   = stats + 4096;     // 4096 (unused)
    float* route    = stats + 8192;     // 32
    float* fw       = stats + 8256;     // 3
    float* mean1    = stats + 8320;     // 1024
    float* istd1    = mean1 + 1024;
    float* ag1      = istd1 + 1024;
    float* ab1      = ag1 + 1024;
    float* mean2    = ab1 + 1024;       // 4096
    float* istd2    = mean2 + 4096;
    float* ag2      = istd2 + 4096;
    float* ab2      = ag2 + 4096;

    // 1. global pooled stats of x (mean only used) + routing softmax
    channel_stats_kernel<<<dim3(BB * CC), 256, 0, stream>>>(x, pooled_x, istd_x);
    router_kernel<<<1, 64, 0, stream>>>(pooled_x, rw, rb, fwts, route, fw);

    // 2. branch 1: conv1 -> AFN1 -> GELU -> conv2 -> AFN2 = out1
    conv3x3_kernel<256, 64, 8><<<dim3(36, 8, 16), 256, 0, stream>>>(x, c1w, c1b, h1);
    channel_stats_kernel<<<dim3(BB * C4), 256, 0, stream>>>(h1, mean1, istd1);
    afn_mlp_kernel<64, 16><<<dim3(BB), 128, 0, stream>>>(mean1, s1w1, s1b1, s2w1, s2b1, ag1, ab1);
    afn_apply_kernel<64, true><<<dim3(36, 64, 16), 256, 0, stream>>>(h1, mean1, istd1, ag1, ab1, g1, be1);
    conv3x3_kernel<64, 256, 8><<<dim3(36, 32, 16), 256, 0, stream>>>(h1, c2w, c2b, h2);
    channel_stats_kernel<<<dim3(BB * CC), 256, 0, stream>>>(h2, mean2, istd2);
    afn_mlp_kernel<256, 64><<<dim3(BB), 512, 0, stream>>>(mean2, s1w2, s1b2, s2w2, s2b2, ag2, ab2);
    afn_apply_kernel<256, false><<<dim3(36, 256, 16), 256, 0, stream>>>(h2, mean2, istd2, ag2, ab2, g2, be2);

    // 3. out = x + route0 * out1   (h2/out1 dead after this; region0 freed for qkv)
    combine_kernel<<<dim3(9216, 16), 256, 0, stream>>>(x, h2, route, out);

    // 4. attention branch
    qkv_kernel<8><<<dim3(36, 96, 16), 256, 0, stream>>>(x, qkvw, qkvb, qkv);
    attn_kernel<<<dim3(32, 8, 16), 256, 0, stream>>>(qkv, abuf);
    proj_acc_kernel<8><<<dim3(36, 32, 16), 256, 0, stream>>>(abuf, pjw, pjb, route, out);

    // 5. frequency branches (sequential, reuse ftmp)
    for (int i = 0; i < 3; ++i) {
        freqdw_kernel<<<dim3(36, 64, 16), 256, 0, stream>>>(x, dww + i * C4 * 36, dwb + i * C4, ftmp);
        freqpw_acc_kernel<8><<<dim3(36, 32, 16), 256, 0, stream>>>(ftmp, pww + i * CC * C4,
                                                                   pwb + i * CC, route, fw, i, out);
    }
}

// Round 3
// 1648.141 us; speedup vs baseline: 2.9493x; 2.9493x over previous
//
#include <hip/hip_runtime.h>
#include <hip/hip_bf16.h>
#include <math.h>
#include <stdint.h>

#define BB 16
#define CC 256
#define C4 64
#define HH 96
#define WW 96
#define HW 9216
#define EPSF 1e-5f

using bf16x8 = __attribute__((ext_vector_type(8))) short;
using f32x4  = __attribute__((ext_vector_type(4))) float;

#define GLD16(g, l) \
    __builtin_amdgcn_global_load_lds((const __attribute__((address_space(1))) unsigned int*)(g), \
                                     (__attribute__((address_space(3))) unsigned int*)(l), 16, 0, 0)

// ---------------- tiny zero-page init ----------------
__global__ void zero_kernel(unsigned int* __restrict__ p) { p[threadIdx.x] = 0u; }

// ---------------- per-channel mean + inv_std (var uses n-1) ----------------
__global__ void channel_stats_kernel(const float* __restrict__ x,
                                     float* __restrict__ mean_out,
                                     float* __restrict__ istd_out) {
    int bc = blockIdx.x;
    const float* p = x + (size_t)bc * HW;
    float s = 0.f, ss = 0.f;
    for (int i = threadIdx.x; i < HW; i += 256) { float v = p[i]; s += v; ss += v * v; }
    __shared__ float red[256], red2[256];
    red[threadIdx.x] = s; red2[threadIdx.x] = ss;
    __syncthreads();
    for (int off = 128; off > 0; off >>= 1) {
        if (threadIdx.x < off) { red[threadIdx.x] += red[threadIdx.x + off]; red2[threadIdx.x] += red2[threadIdx.x + off]; }
        __syncthreads();
    }
    if (threadIdx.x == 0) {
        float sum = red[0], sumsq = red2[0];
        float m = sum / (float)HW;
        float var = (sumsq - sum * m) / (float)(HW - 1);
        mean_out[bc] = m;
        istd_out[bc] = rsqrtf(var + EPSF);
    }
}

// ---------------- router softmax + freq-weight softmax ----------------
__global__ void router_kernel(const float* __restrict__ pooled, const float* __restrict__ rw,
                              const float* __restrict__ rb, const float* __restrict__ fwts,
                              float* __restrict__ route, float* __restrict__ fw) {
    int t = threadIdx.x;
    if (t < BB) {
        float l0 = rb[0], l1 = rb[1];
        for (int c = 0; c < CC; ++c) {
            float p = pooled[t * CC + c];
            l0 += p * rw[c];
            l1 += p * rw[CC + c];
        }
        float m = fmaxf(l0, l1);
        float e0 = __expf(l0 - m), e1 = __expf(l1 - m);
        float inv = 1.f / (e0 + e1);
        route[t * 2 + 0] = e0 * inv;
        route[t * 2 + 1] = e1 * inv;
    }
    if (t == BB) {
        float a = fwts[0], b = fwts[1], c = fwts[2];
        float m = fmaxf(a, fmaxf(b, c));
        float e0 = __expf(a - m), e1 = __expf(b - m), e2 = __expf(c - m);
        float inv = 1.f / (e0 + e1 + e2);
        fw[0] = e0 * inv; fw[1] = e1 * inv; fw[2] = e2 * inv;
    }
}

// ---------------- weight prep ----------------
__global__ void pack_w3x3_kernel(const float* __restrict__ w, __hip_bfloat16* __restrict__ wt,
                                 int COUT, int CINW) {
    int idx = blockIdx.x * 256 + threadIdx.x;
    int total = COUT * 9 * CINW;
    if (idx >= total) return;
    int ci = idx % CINW; int rest = idx / CINW; int tau = rest % 9; int co = rest / 9;
    wt[idx] = __float2bfloat16(w[((size_t)co * CINW + ci) * 9 + tau]);
}

__global__ void cast_w_kernel(const float* __restrict__ w, __hip_bfloat16* __restrict__ o, int n) {
    int idx = blockIdx.x * 256 + threadIdx.x;
    if (idx < n) o[idx] = __float2bfloat16(w[idx]);
}

// pww (3,256,64) + fw -> wtf (256,192) scaled; fbias[co] = sum fw[i]*pwb[i][co]
__global__ void fuse_freq_w_kernel(const float* __restrict__ pww, const float* __restrict__ pwb,
                                   const float* __restrict__ fw, __hip_bfloat16* __restrict__ wtf,
                                   float* __restrict__ fbias) {
    int co = blockIdx.x; int t = threadIdx.x;  // 192 threads
    int i = t >> 6, g = t & 63;
    wtf[co * 192 + t] = __float2bfloat16(fw[i] * pww[((size_t)(i * 256 + co)) * 64 + g]);
    if (t == 0) fbias[co] = fw[0] * pwb[co] + fw[1] * pwb[256 + co] + fw[2] * pwb[512 + co];
}

// ---------------- planar (B,CIN,HW) -> pixel-major (B,HW,CIN) bf16 ----------------
__device__ inline float to_f32(float v) { return v; }
__device__ inline float to_f32(__hip_bfloat16 v) { return __bfloat162float(v); }

template <typename TIN, int CIN>
__global__ __launch_bounds__(256) void transpose_pm_kernel(const TIN* __restrict__ x,
                                                           __hip_bfloat16* __restrict__ xt) {
    __shared__ float s[32][33];
    int p0 = blockIdx.x * 32, c0 = blockIdx.y * 32, b = blockIdx.z;
    int tx = threadIdx.x, ty = threadIdx.y;  // (32,8)
    const TIN* xp = x + ((size_t)b * CIN + c0) * HW + p0;
#pragma unroll
    for (int i = 0; i < 4; ++i) {
        int c = ty * 4 + i;
        s[c][tx] = to_f32(xp[(size_t)c * HW + tx]);
    }
    __syncthreads();
    __hip_bfloat16* yp = xt + ((size_t)b * HW + p0) * CIN + c0;
#pragma unroll
    for (int i = 0; i < 4; ++i) {
        int r = ty * 4 + i;
        yp[(size_t)r * CIN + tx] = __float2bfloat16(s[tx][r]);
    }
}

// ---------------- MFMA implicit-GEMM conv ----------------
// A: [CO_TOT][TSH*KC] bf16 weights; Bx: [.][9216][CDIM] bf16 pixel-major
// EPI: 0=f32 planar store, 1=bf16 planar store, 2=f32 planar += route[b]*val
// bin0/bout0: batch offsets for input/route vs output indexing.
template <int BM, int BN, int TSH, int KC, int CDIM, int EPI, int CO_TOT>
__global__ __launch_bounds__(256) void mfma_gemm_kernel(const short* __restrict__ A,
                                                        const short* __restrict__ Bx,
                                                        const short* __restrict__ zp,
                                                        const float* __restrict__ bias,
                                                        const float* __restrict__ route,
                                                        void* __restrict__ Y,
                                                        int bin0, int bout0) {
    constexpr int WM = BM / 2, WN = BN / 2;
    constexpr int FM = WM / 16, FN = WN / 16;
    constexpr int KB = KC / 32;
    constexpr int NA = BM / 16;
    constexpr int NB = BN / 16;
    __shared__ __align__(16) short As[BM * 32];
    __shared__ __align__(16) short Bs[BN * 32];
    int tid = threadIdx.x;
    int wid = tid >> 6, lane = tid & 63;
    int wy = wid >> 1, wx = wid & 1;
    int lane16 = lane & 15, quad = lane >> 4;
    int lrow = lane >> 2, lchk = lane & 3;
    int co0 = blockIdx.x * BM;
    int n0 = blockIdx.y * BN;
    int bin = blockIdx.z + bin0;
    int bout = blockIdx.z + bout0;

    f32x4 acc[FM][FN];
#pragma unroll
    for (int i = 0; i < FM; ++i)
#pragma unroll
        for (int j = 0; j < FN; ++j) acc[i][j] = (f32x4){0.f, 0.f, 0.f, 0.f};

    const short* Bbase = Bx + (size_t)bin * HW * CDIM;

    for (int tau = 0; tau < TSH; ++tau) {
        int dh = tau / 3, dw = tau % 3;
        int off = (TSH > 1) ? (dh - 1) * 96 + (dw - 1) : 0;
        for (int kb = 0; kb < KB; ++kb) {
            int kc0 = kb * 32;
#pragma unroll
            for (int t = 0; t < NA / 4; ++t) {
                int inst = wid * (NA / 4) + t;
                int row = inst * 16 + lrow;
                const short* g = A + (size_t)(co0 + row) * (TSH * KC) + tau * KC + kc0 + lchk * 8;
                GLD16(g, &As[inst * 512]);
            }
#pragma unroll
            for (int t = 0; t < NB / 4; ++t) {
                int inst = wid * (NB / 4) + t;
                int row = inst * 16 + lrow;
                int n = n0 + row;
                const short* g;
                if (TSH > 1) {
                    int h = n / 96, w = n - h * 96;
                    int hh = h + dh - 1, ww2 = w + dw - 1;
                    bool valid = ((unsigned)hh < 96u) && ((unsigned)ww2 < 96u);
                    g = valid ? (Bbase + (size_t)(n + off) * CDIM + kc0 + lchk * 8) : zp;
                } else {
                    g = Bbase + (size_t)n * CDIM + kc0 + lchk * 8;
                }
                GLD16(g, &Bs[inst * 512]);
            }
            __syncthreads();
            bf16x8 af[FM], bfr[FN];
#pragma unroll
            for (int i = 0; i < FM; ++i)
                af[i] = *(const bf16x8*)&As[(wy * WM + i * 16 + lane16) * 32 + quad * 8];
#pragma unroll
            for (int j = 0; j < FN; ++j)
                bfr[j] = *(const bf16x8*)&Bs[(wx * WN + j * 16 + lane16) * 32 + quad * 8];
#pragma unroll
            for (int i = 0; i < FM; ++i)
#pragma unroll
                for (int j = 0; j < FN; ++j)
                    acc[i][j] = __builtin_amdgcn_mfma_f32_16x16x32_bf16(af[i], bfr[j], acc[i][j], 0, 0, 0);
            __syncthreads();
        }
    }
    float scale = 1.f;
    if (EPI == 2) scale = route[bin * 2 + 1];
#pragma unroll
    for (int i = 0; i < FM; ++i) {
        int co_l = co0 + wy * WM + i * 16 + quad * 4;
#pragma unroll
        for (int j = 0; j < FN; ++j) {
            int pix = n0 + wx * WN + j * 16 + lane16;
#pragma unroll
            for (int r = 0; r < 4; ++r) {
                int co = co_l + r;
                float v = acc[i][j][r] + bias[co];
                size_t idx = ((size_t)(bout * CO_TOT + co)) * HW + pix;
                if (EPI == 0) ((float*)Y)[idx] = v;
                else if (EPI == 1) ((__hip_bfloat16*)Y)[idx] = __float2bfloat16(v);
                else ((float*)Y)[idx] += scale * v;
            }
        }
    }
}

// ---------------- AFN tiny MLP ----------------
template <int CH, int HID>
__global__ void afn_mlp_kernel(const float* __restrict__ mean,
                               const float* __restrict__ s1w, const float* __restrict__ s1b,
                               const float* __restrict__ s2w, const float* __restrict__ s2b,
                               float* __restrict__ ag, float* __restrict__ ab) {
    int b = blockIdx.x;
    __shared__ float hbuf[HID];
    int t = threadIdx.x;
    if (t < HID) {
        float s = s1b[t];
        for (int c = 0; c < CH; ++c) s += mean[b * CH + c] * s1w[t * CH + c];
        hbuf[t] = fmaxf(s, 0.f);
    }
    __syncthreads();
    if (t < 2 * CH) {
        float s = s2b[t];
#pragma unroll
        for (int k = 0; k < HID; ++k) s += hbuf[k] * s2w[t * HID + k];
        if (t < CH) ag[b * CH + t] = s;
        else        ab[b * CH + (t - CH)] = s;
    }
}

// ---------------- AFN apply (+ optional exact GELU), in place ----------------
template <int CH, bool GELU>
__global__ void afn_apply_kernel(float* __restrict__ hbuf_g, const float* __restrict__ mean,
                                 const float* __restrict__ istd, const float* __restrict__ ag,
                                 const float* __restrict__ ab, const float* __restrict__ gamma,
                                 const float* __restrict__ beta) {
    int p = blockIdx.x * 256 + threadIdx.x;
    int c = blockIdx.y, b = blockIdx.z;
    int bc = b * CH + c;
    float scale = (1.f + ag[bc]) * gamma[c] * istd[bc];
    float shift = ab[bc] * beta[c];
    float m = mean[bc];
    float* ptr = hbuf_g + (size_t)bc * HW + p;
    float v = (*ptr - m) * scale + shift;
    if (GELU) v = 0.5f * v * (1.f + erff(v * 0.70710678118654752f));
    *ptr = v;
}

// ---------------- out = x + route0 * out1 ----------------
__global__ void combine_kernel(const float* __restrict__ x, const float* __restrict__ out1,
                               const float* __restrict__ route, float* __restrict__ out) {
    int b = blockIdx.y;
    size_t i = (size_t)b * CC * HW + (size_t)blockIdx.x * 256 + threadIdx.x;
    float r0 = route[b * 2];
    out[i] = x[i] + r0 * out1[i];
}

// ---------------- attention: one block per (b_local, n, d) ----------------
#define LP 98
__global__ __launch_bounds__(256) void attn_kernel(const __hip_bfloat16* __restrict__ qkv,
                                                   __hip_bfloat16* __restrict__ a, int bout0) {
    int d = blockIdx.x, n = blockIdx.y, b = blockIdx.z;
    __shared__ __hip_bfloat16 qs[96 * LP];
    __shared__ __hip_bfloat16 ks[96 * LP];
    __shared__ __hip_bfloat16 ss[96 * LP];
    int t = threadIdx.x;
    const __hip_bfloat16* qp = qkv + ((size_t)b * 768 + n * 32 + d) * HW;
    const __hip_bfloat16* kp = qp + (size_t)256 * HW;
    const __hip_bfloat16* vp = qp + (size_t)512 * HW;
    for (int i = t; i < HW; i += 256) {
        int r = i / 96, cc = i % 96;
        qs[r * LP + cc] = qp[i];
        ks[r * LP + cc] = kp[i];
    }
    __syncthreads();
    int tx = t & 15, ty = t >> 4;
    int h0 = ty * 6, g0 = tx * 6;
    float acc[6][6];
#pragma unroll
    for (int i = 0; i < 6; ++i)
#pragma unroll
        for (int j = 0; j < 6; ++j) acc[i][j] = 0.f;
    for (int w = 0; w < 96; ++w) {
        float qv[6], kv[6];
#pragma unroll
        for (int i = 0; i < 6; ++i) qv[i] = __bfloat162float(qs[(h0 + i) * LP + w]);
#pragma unroll
        for (int j = 0; j < 6; ++j) kv[j] = __bfloat162float(ks[(g0 + j) * LP + w]);
#pragma unroll
        for (int i = 0; i < 6; ++i)
#pragma unroll
            for (int j = 0; j < 6; ++j) acc[i][j] += qv[i] * kv[j];
    }
    const float scale = 0.0625f;
#pragma unroll
    for (int i = 0; i < 6; ++i)
#pragma unroll
        for (int j = 0; j < 6; ++j)
            ss[(h0 + i) * LP + g0 + j] = __float2bfloat16(acc[i][j] * scale);
    __syncthreads();
    if (t < 96) {
        float m = -1e30f;
        for (int g = 0; g < 96; ++g) m = fmaxf(m, __bfloat162float(ss[t * LP + g]));
        float sum = 0.f;
        float e[96];
        for (int g = 0; g < 96; ++g) { e[g] = __expf(__bfloat162float(ss[t * LP + g]) - m); sum += e[g]; }
        float inv = 1.f / sum;
        for (int g = 0; g < 96; ++g) ss[t * LP + g] = __float2bfloat16(e[g] * inv);
    }
    __syncthreads();
    for (int i = t; i < HW; i += 256) {
        int r = i / 96, cc = i % 96;
        qs[r * LP + cc] = vp[i];
    }
    __syncthreads();
    int w0 = tx * 6;
#pragma unroll
    for (int i = 0; i < 6; ++i)
#pragma unroll
        for (int j = 0; j < 6; ++j) acc[i][j] = 0.f;
    for (int g = 0; g < 96; ++g) {
        float pv[6], vv[6];
#pragma unroll
        for (int i = 0; i < 6; ++i) pv[i] = __bfloat162float(ss[(h0 + i) * LP + g]);
#pragma unroll
        for (int j = 0; j < 6; ++j) vv[j] = __bfloat162float(qs[g * LP + w0 + j]);
#pragma unroll
        for (int i = 0; i < 6; ++i)
#pragma unroll
            for (int j = 0; j < 6; ++j) acc[i][j] += pv[i] * vv[j];
    }
    __hip_bfloat16* ap = a + ((size_t)(bout0 + b) * CC + (d * 8 + n)) * HW;
#pragma unroll
    for (int i = 0; i < 6; ++i)
#pragma unroll
        for (int j = 0; j < 6; ++j)
            ap[(h0 + i) * 96 + w0 + j] = __float2bfloat16(acc[i][j]);
}

// ---------------- grouped 3x3 conv + exact GELU -> bf16 planar ----------------
__global__ __launch_bounds__(256) void freqdw_kernel(const float* __restrict__ x,
                                                     const float* __restrict__ wgt,
                                                     const float* __restrict__ bias,
                                                     __hip_bfloat16* __restrict__ f, int cbase) {
    int p = blockIdx.x * 256 + threadIdx.x;
    int g = blockIdx.y;
    int b = blockIdx.z;
    int h = p / WW, w = p % WW;
    float acc = bias[g];
    const float* wq = wgt + g * 36;
#pragma unroll
    for (int q = 0; q < 4; ++q) {
        const float* xc = x + ((size_t)b * CC + 4 * g + q) * HW;
#pragma unroll
        for (int dh = 0; dh < 3; ++dh) {
            int hh = h + dh - 1;
            bool hv = (hh >= 0) && (hh < HH);
#pragma unroll
            for (int dw = 0; dw < 3; ++dw) {
                int ww2 = w + dw - 1;
                bool v = hv && (ww2 >= 0) && (ww2 < WW);
                float xv = v ? xc[hh * WW + ww2] : 0.f;
                acc += xv * wq[q * 9 + dh * 3 + dw];
            }
        }
    }
    acc = 0.5f * acc * (1.f + erff(acc * 0.70710678118654752f));
    f[((size_t)b * 192 + cbase + g) * HW + p] = __float2bfloat16(acc);
}

extern "C" void kernel_launch(void* const* d_in, const int* in_sizes, int n_in,
                              void* d_out, int out_size, void* d_ws, size_t ws_size,
                              hipStream_t stream) {
    const float* x    = (const float*)d_in[0];
    const float* c1w  = (const float*)d_in[1];
    const float* c1b  = (const float*)d_in[2];
    const float* g1   = (const float*)d_in[3];
    const float* be1  = (const float*)d_in[4];
    const float* s1w1 = (const float*)d_in[5];
    const float* s1b1 = (const float*)d_in[6];
    const float* s2w1 = (const float*)d_in[7];
    const float* s2b1 = (const float*)d_in[8];
    const float* c2w  = (const float*)d_in[9];
    const float* c2b  = (const float*)d_in[10];
    const float* g2   = (const float*)d_in[11];
    const float* be2  = (const float*)d_in[12];
    const float* s1w2 = (const float*)d_in[13];
    const float* s1b2 = (const float*)d_in[14];
    const float* s2w2 = (const float*)d_in[15];
    const float* s2b2 = (const float*)d_in[16];
    const float* qkvw = (const float*)d_in[17];
    const float* qkvb = (const float*)d_in[18];
    const float* pjw  = (const float*)d_in[19];
    const float* pjb  = (const float*)d_in[20];
    const float* dww  = (const float*)d_in[21];
    const float* dwb  = (const float*)d_in[22];
    const float* pww  = (const float*)d_in[23];
    const float* pwb  = (const float*)d_in[24];
    const float* fwts = (const float*)d_in[25];
    const float* rw   = (const float*)d_in[26];
    const float* rb   = (const float*)d_in[27];
    float* out = (float*)d_out;
    (void)ws_size;

    char* ws = (char*)d_ws;
    // ---- workspace map (peak ~284.4 MB; round-1 proved >=302.1 MB is safe) ----
    // [0,151.0M): h2 f32 (phase1); later qkvs bf16 (8 batches, 113.25M) / at_t / fall / f_t
    float* h2 = (float*)ws;
    __hip_bfloat16* qkvs = (__hip_bfloat16*)ws;                      // 113,246,208 B
    __hip_bfloat16* at_t = (__hip_bfloat16*)ws;                      //  75,497,472 B
    __hip_bfloat16* fall = (__hip_bfloat16*)ws;                      //  56,623,104 B
    __hip_bfloat16* f_t  = (__hip_bfloat16*)(ws + 56623104ULL);      //  56,623,104 B
    // [151.0M, 188.7M): h1 f32
    float* h1 = (float*)(ws + 150994944ULL);
    // [188.7M, 207.6M): h1t bf16
    __hip_bfloat16* h1t = (__hip_bfloat16*)(ws + 188743680ULL);
    // [207.6M, 283.1M): xt bf16 (B,HW,256); per-half overwritten by at (planar bf16)
    __hip_bfloat16* xt = (__hip_bfloat16*)(ws + 207618048ULL);
    __hip_bfloat16* at = xt;
    // tail [283.1M, ~284.4M): zero page + stats + bf16 weights
    const size_t TB = 283115520ULL;
    short* zp = (short*)(ws + TB);            // 256 B
    float* stats = (float*)(ws + TB + 256);
    float* pooled_x = stats;                  // 4096
    float* route    = pooled_x + 4096;        // 32
    float* fw       = route + 32;             // 4
    float* mean1    = fw + 4;                 // 1024
    float* istd1    = mean1 + 1024;
    float* ag1      = istd1 + 1024;
    float* ab1      = ag1 + 1024;
    float* mean2    = ab1 + 1024;             // 4096
    float* istd2    = mean2 + 4096;
    float* ag2      = istd2 + 4096;
    float* ab2      = ag2 + 4096;
    float* fbias    = ab2 + 4096;             // 256
    float* dummy    = fbias + 256;            // 4096
    char* wbase = (char*)(dummy + 4096);
    __hip_bfloat16* wt1  = (__hip_bfloat16*)wbase;              // 64*9*256
    __hip_bfloat16* wt2  = (__hip_bfloat16*)(wbase + 294912);   // 256*9*64
    __hip_bfloat16* qw16 = (__hip_bfloat16*)(wbase + 589824);   // 768*256
    __hip_bfloat16* pw16 = (__hip_bfloat16*)(wbase + 983040);   // 256*256
    __hip_bfloat16* wtf  = (__hip_bfloat16*)(wbase + 1114112);  // 256*192

    zero_kernel<<<1, 64, 0, stream>>>((unsigned int*)zp);

    // stats + routing
    channel_stats_kernel<<<dim3(BB * CC), 256, 0, stream>>>(x, pooled_x, dummy);
    router_kernel<<<1, 64, 0, stream>>>(pooled_x, rw, rb, fwts, route, fw);

    // weight prep
    pack_w3x3_kernel<<<576, 256, 0, stream>>>(c1w, wt1, 64, 256);
    pack_w3x3_kernel<<<576, 256, 0, stream>>>(c2w, wt2, 256, 64);
    cast_w_kernel<<<768, 256, 0, stream>>>(qkvw, qw16, 768 * 256);
    cast_w_kernel<<<256, 256, 0, stream>>>(pjw, pw16, 256 * 256);
    fuse_freq_w_kernel<<<256, 192, 0, stream>>>(pww, pwb, fw, wtf, fbias);

    // x -> pixel-major bf16
    transpose_pm_kernel<float, 256><<<dim3(288, 8, 16), dim3(32, 8), 0, stream>>>(x, xt);

    // branch 1: conv1 -> AFN1+GELU -> conv2 -> AFN2
    mfma_gemm_kernel<64, 128, 9, 256, 256, 0, 64>
        <<<dim3(1, 72, 16), 256, 0, stream>>>((const short*)wt1, (const short*)xt, zp, c1b, nullptr, h1, 0, 0);
    channel_stats_kernel<<<dim3(BB * C4), 256, 0, stream>>>(h1, mean1, istd1);
    afn_mlp_kernel<64, 16><<<dim3(BB), 128, 0, stream>>>(mean1, s1w1, s1b1, s2w1, s2b1, ag1, ab1);
    afn_apply_kernel<64, true><<<dim3(36, 64, 16), 256, 0, stream>>>(h1, mean1, istd1, ag1, ab1, g1, be1);
    transpose_pm_kernel<float, 64><<<dim3(288, 2, 16), dim3(32, 8), 0, stream>>>(h1, h1t);
    mfma_gemm_kernel<128, 128, 9, 64, 64, 0, 256>
        <<<dim3(2, 72, 16), 256, 0, stream>>>((const short*)wt2, (const short*)h1t, zp, c2b, nullptr, h2, 0, 0);
    channel_stats_kernel<<<dim3(BB * CC), 256, 0, stream>>>(h2, mean2, istd2);
    afn_mlp_kernel<256, 64><<<dim3(BB), 512, 0, stream>>>(mean2, s1w2, s1b2, s2w2, s2b2, ag2, ab2);
    afn_apply_kernel<256, false><<<dim3(36, 256, 16), 256, 0, stream>>>(h2, mean2, istd2, ag2, ab2, g2, be2);

    // out = x + r0*out1  (h2 dead afterwards -> region reused for qkvs)
    combine_kernel<<<dim3(9216, 16), 256, 0, stream>>>(x, h2, route, out);

    // attention branch, two batch-halves sharing the qkv scratch
    for (int half = 0; half < 2; ++half) {
        mfma_gemm_kernel<128, 128, 1, 256, 256, 1, 768>
            <<<dim3(6, 72, 8), 256, 0, stream>>>((const short*)qw16, (const short*)xt, zp, qkvb,
                                                 nullptr, qkvs, half * 8, 0);
        attn_kernel<<<dim3(32, 8, 8), 256, 0, stream>>>(qkvs, at, half * 8);
    }
    transpose_pm_kernel<__hip_bfloat16, 256><<<dim3(288, 8, 16), dim3(32, 8), 0, stream>>>(at, at_t);
    mfma_gemm_kernel<128, 128, 1, 256, 256, 2, 256>
        <<<dim3(2, 72, 16), 256, 0, stream>>>((const short*)pw16, (const short*)at_t, zp, pjb, route, out, 0, 0);

    // frequency branches: 3 dw convs -> fall (B,192,HW) bf16, one fused GEMM
    for (int i = 0; i < 3; ++i)
        freqdw_kernel<<<dim3(36, 64, 16), 256, 0, stream>>>(x, dww + i * C4 * 36, dwb + i * C4, fall, i * 64);
    transpose_pm_kernel<__hip_bfloat16, 192><<<dim3(288, 6, 16), dim3(32, 8), 0, stream>>>(fall, f_t);
    mfma_gemm_kernel<128, 128, 1, 192, 192, 2, 256>
        <<<dim3(2, 72, 16), 256, 0, stream>>>((const short*)wtf, (const short*)f_t, zp, fbias, route, out, 0, 0);
}